// Round 1
// 18067.543 us; speedup vs baseline: 1.2124x; 1.2124x over previous
//
#include <hip/hip_runtime.h>
#include <cstddef>
#include <cstdint>

#define H      1024
#define HP     1025
#define OUTD   32
#define ACTD   8
#define BATCH  128
#define TSTEPS 255
#define G3     3072
#define LOG2PI 1.8378770664093453f

typedef __bf16 bf16x8 __attribute__((ext_vector_type(8)));
typedef float  f32x4  __attribute__((ext_vector_type(4)));
typedef unsigned int u32x4v __attribute__((ext_vector_type(4)));

__device__ __forceinline__ unsigned short f2bf(float x) {
  unsigned int u = __float_as_uint(x);
  unsigned int r = (u + 0x7fffu + ((u >> 16) & 1u)) >> 16;  // RNE
  return (unsigned short)r;
}
__device__ __forceinline__ float bflo(unsigned int u) { return __uint_as_float(u << 16); }
__device__ __forceinline__ bf16x8 ldb8(const unsigned short* p) {
  return *(const bf16x8*)(const void*)p;
}
// int8 byte k of dword v -> float (v_bfe_i32 + v_cvt_f32_i32)
__device__ __forceinline__ float i8f(unsigned int v, int k) {
  return (float)(int)(signed char)(v >> (k * 8));
}

// ---------------------------------------------------------------------------
// Naive f32 GEMM (encoder only, runs once): C = act(A[M,K] @ B[N,K]^T + bias)
// ---------------------------------------------------------------------------
template <int ACTMODE>
__global__ __launch_bounds__(256) void gemm_nt(const float* __restrict__ A,
                                               const float* __restrict__ Bm,
                                               const float* __restrict__ bias,
                                               float* __restrict__ C,
                                               int M, int N, int K) {
  __shared__ float As[32][33];
  __shared__ float Bs[32][33];
  const int bm = blockIdx.y, bn = blockIdx.x;
  const int t = threadIdx.x;
  const int tr = t >> 5, tc = t & 31;
  float acc0 = 0.f, acc1 = 0.f, acc2 = 0.f, acc3 = 0.f;
  for (int k0 = 0; k0 < K; k0 += 32) {
#pragma unroll
    for (int e = 0; e < 4; ++e) {
      int idx = t + e * 256;
      int r = idx >> 5, c = idx & 31;
      As[r][c] = A[(size_t)(bm * 32 + r) * K + (k0 + c)];
      Bs[r][c] = Bm[(size_t)(bn * 32 + r) * K + (k0 + c)];
    }
    __syncthreads();
#pragma unroll
    for (int kk = 0; kk < 32; ++kk) {
      float bv = Bs[tc][kk];
      acc0 = fmaf(As[tr][kk], bv, acc0);
      acc1 = fmaf(As[tr + 8][kk], bv, acc1);
      acc2 = fmaf(As[tr + 16][kk], bv, acc2);
      acc3 = fmaf(As[tr + 24][kk], bv, acc3);
    }
    __syncthreads();
  }
  const float bv = bias[bn * 32 + tc];
  float vals[4] = {acc0 + bv, acc1 + bv, acc2 + bv, acc3 + bv};
#pragma unroll
  for (int i2 = 0; i2 < 4; ++i2) {
    float v = vals[i2];
    if (ACTMODE == 1) v = v > 0.f ? v : 0.f;
    if (ACTMODE == 2) v = tanhf(v);
    C[(size_t)(bm * 32 + tr + i2 * 8) * N + (bn * 32 + tc)] = v;
  }
}

// ---------------------------------------------------------------------------
// K1: fused per-step kernel, two block roles (unchanged this round).
// ---------------------------------------------------------------------------
__global__ __launch_bounds__(256) void step_fused(
    const unsigned short* __restrict__ hb, const float* __restrict__ hprev,
    const unsigned short* __restrict__ gwhhb, const float* __restrict__ w_ih,
    const float* __restrict__ b_ih, const float* __restrict__ gb_hh,
    const float* __restrict__ a_t, float* __restrict__ f,
    const unsigned short* __restrict__ decwb, const float* __restrict__ dec_b,
    const unsigned short* __restrict__ headwb, float* __restrict__ Pbuf,
    int nRoleA) {
  const int wv = threadIdx.x >> 6;
  const int lane = threadIdx.x & 63;
  const int row = lane & 15, kq = lane >> 4;
  const int col = lane & 15, rbase = (lane >> 4) * 4;
  __shared__ unsigned short decls[16][264];  // Role B staging (padded stride)

  if ((int)blockIdx.x < nRoleA) {
    // ---------------- Role A ----------------
    const int mt = blockIdx.x >> 4, ng = blockIdx.x & 15;
    const int b0 = mt * 16;
    const int i0 = (ng * 4 + wv) * 16;
    const unsigned short* ap = hb + (size_t)(b0 + row) * H + kq * 8;
    const unsigned short* bpr = gwhhb + (size_t)(i0 + row) * H + kq * 8;
    const unsigned short* bpz = bpr + (size_t)H * H;
    const unsigned short* bpn = bpr + 2 * (size_t)H * H;
    f32x4 ar0 = {0.f, 0.f, 0.f, 0.f}, ar1 = ar0, az0 = ar0, az1 = ar0, an0 = ar0, an1 = ar0;
    for (int k0 = 0; k0 < H; k0 += 64) {
      bf16x8 a0 = ldb8(ap + k0);
      bf16x8 a1 = ldb8(ap + k0 + 32);
      ar0 = __builtin_amdgcn_mfma_f32_16x16x32_bf16(a0, ldb8(bpr + k0), ar0, 0, 0, 0);
      ar1 = __builtin_amdgcn_mfma_f32_16x16x32_bf16(a1, ldb8(bpr + k0 + 32), ar1, 0, 0, 0);
      az0 = __builtin_amdgcn_mfma_f32_16x16x32_bf16(a0, ldb8(bpz + k0), az0, 0, 0, 0);
      az1 = __builtin_amdgcn_mfma_f32_16x16x32_bf16(a1, ldb8(bpz + k0 + 32), az1, 0, 0, 0);
      an0 = __builtin_amdgcn_mfma_f32_16x16x32_bf16(a0, ldb8(bpn + k0), an0, 0, 0, 0);
      an1 = __builtin_amdgcn_mfma_f32_16x16x32_bf16(a1, ldb8(bpn + k0 + 32), an1, 0, 0, 0);
    }
    f32x4 AR = ar0 + ar1, AZ = az0 + az1, AN = an0 + an1;
    const int i = i0 + col;
    const float bihr = b_ih[i], bihz = b_ih[H + i], bihn = b_ih[2 * H + i];
    const float bhr = gb_hh[i], bhz = gb_hh[H + i], bhn = gb_hh[2 * H + i];
    const float4* wi = (const float4*)(const void*)(w_ih + (size_t)i * ACTD);
    const float4* wzp = (const float4*)(const void*)(w_ih + (size_t)(H + i) * ACTD);
    const float4* wnp = (const float4*)(const void*)(w_ih + (size_t)(2 * H + i) * ACTD);
    const float4 wr0 = wi[0], wr1 = wi[1];
    const float4 wz0 = wzp[0], wz1 = wzp[1];
    const float4 wn0 = wnp[0], wn1 = wnp[1];
#pragma unroll
    for (int r = 0; r < 4; ++r) {
      const int b = b0 + rbase + r;
      const float4* at = (const float4*)(const void*)(a_t + (size_t)b * ACTD);
      const float4 a0 = at[0], a1 = at[1];
      float gir = bihr, giz = bihz, gin = bihn;
      gir = fmaf(a0.x, wr0.x, gir); gir = fmaf(a0.y, wr0.y, gir);
      gir = fmaf(a0.z, wr0.z, gir); gir = fmaf(a0.w, wr0.w, gir);
      gir = fmaf(a1.x, wr1.x, gir); gir = fmaf(a1.y, wr1.y, gir);
      gir = fmaf(a1.z, wr1.z, gir); gir = fmaf(a1.w, wr1.w, gir);
      giz = fmaf(a0.x, wz0.x, giz); giz = fmaf(a0.y, wz0.y, giz);
      giz = fmaf(a0.z, wz0.z, giz); giz = fmaf(a0.w, wz0.w, giz);
      giz = fmaf(a1.x, wz1.x, giz); giz = fmaf(a1.y, wz1.y, giz);
      giz = fmaf(a1.z, wz1.z, giz); giz = fmaf(a1.w, wz1.w, giz);
      gin = fmaf(a0.x, wn0.x, gin); gin = fmaf(a0.y, wn0.y, gin);
      gin = fmaf(a0.z, wn0.z, gin); gin = fmaf(a0.w, wn0.w, gin);
      gin = fmaf(a1.x, wn1.x, gin); gin = fmaf(a1.y, wn1.y, gin);
      gin = fmaf(a1.z, wn1.z, gin); gin = fmaf(a1.w, wn1.w, gin);
      const float rg = 1.f / (1.f + expf(-(gir + AR[r] + bhr)));
      const float zg = 1.f / (1.f + expf(-(giz + AZ[r] + bhz)));
      const float ng_ = tanhf(gin + rg * (AN[r] + bhn));
      const float hp = hprev[(size_t)b * H + i];
      f[(size_t)b * H + i] = (1.f - zg) * ng_ + zg * hp;
    }
    return;
  }

  // ---------------- Role B ----------------
  const int rb = (int)blockIdx.x - nRoleA;
  const int b0 = (rb >> 2) * 16;
  const int J0 = (rb & 3) * 256;
  const unsigned short* ap = hb + (size_t)(b0 + row) * H + kq * 8;
#pragma unroll
  for (int tt = 0; tt < 4; ++tt) {
    const int j0 = J0 + (wv * 4 + tt) * 16;
    const unsigned short* bp = decwb + (size_t)(j0 + row) * H + kq * 8;
    f32x4 c0 = {0.f, 0.f, 0.f, 0.f}, c1 = c0;
    for (int k0 = 0; k0 < H; k0 += 64) {
      c0 = __builtin_amdgcn_mfma_f32_16x16x32_bf16(ldb8(ap + k0), ldb8(bp + k0), c0, 0, 0, 0);
      c1 = __builtin_amdgcn_mfma_f32_16x16x32_bf16(ldb8(ap + k0 + 32), ldb8(bp + k0 + 32), c1, 0, 0, 0);
    }
    f32x4 d = c0 + c1;
    const float db = dec_b[j0 + col];
#pragma unroll
    for (int r = 0; r < 4; ++r) {
      float v = d[r] + db;
      v = v > 0.f ? v : 0.f;
      decls[rbase + r][j0 - J0 + col] = f2bf(v);
    }
  }
  __syncthreads();
  {
    const int o0 = wv * 16;
    const unsigned short* hp2 = headwb + (size_t)(o0 + row) * H + J0 + kq * 8;
    f32x4 c0 = {0.f, 0.f, 0.f, 0.f}, c1 = c0;
#pragma unroll
    for (int k0 = 0; k0 < 256; k0 += 64) {
      bf16x8 a0 = *(const bf16x8*)(const void*)&decls[row][k0 + kq * 8];
      bf16x8 a1 = *(const bf16x8*)(const void*)&decls[row][k0 + 32 + kq * 8];
      c0 = __builtin_amdgcn_mfma_f32_16x16x32_bf16(a0, ldb8(hp2 + k0), c0, 0, 0, 0);
      c1 = __builtin_amdgcn_mfma_f32_16x16x32_bf16(a1, ldb8(hp2 + k0 + 32), c1, 0, 0, 0);
    }
    f32x4 d = c0 + c1;
#pragma unroll
    for (int r = 0; r < 4; ++r)
      atomicAdd(&Pbuf[(size_t)(b0 + rbase + r) * 64 + o0 + col], d[r]);
  }
}

// ---------------------------------------------------------------------------
// K2: HBM/L3 streamer over int8 W. Blocks [0,4096): 32 rows/block
// (4 waves x 8 rows). Each lane owns 16 consecutive columns of each row:
// one u32x4 (16 int8) per row + 4 float4 of f straight from global (L2/L3-
// served, 64x reuse per batch row) -- no LDS staging, no __syncthreads.
// Dot in f32 after bfe+cvt unpack; per-row scale applied at the end.
// W is 134 MB (< 256 MB L3): plain loads (NO nontemporal) so steps 2..255
// hit Infinity Cache.
// Block 4096: log-likelihood for the PREVIOUS step from Pbuf, then zero Pbuf.
// ---------------------------------------------------------------------------
__global__ __launch_bounds__(256) void wmatvec2(
    const u32x4v* __restrict__ Wq4, const float* __restrict__ Wsc,
    const unsigned short* __restrict__ Wlast, const float* __restrict__ f,
    float* __restrict__ h, unsigned short* __restrict__ hb,
    float* __restrict__ Pbuf, const float* __restrict__ em_b,
    const float* __restrict__ ev_b, const float* __restrict__ Xt,
    float* __restrict__ LL_acc, int llflag) {
  if (blockIdx.x >= 4096) {
    __shared__ float red[256];
    float ll = 0.f;
    if (llflag) {
      for (int it = threadIdx.x; it < BATCH * OUTD; it += 256) {
        const int b = it >> 5, o = it & 31;
        const float mean = Pbuf[b * 64 + o] + em_b[o];
        const float lv = Pbuf[b * 64 + 32 + o] + ev_b[o];
        const float tgt = Xt[b * OUTD + o];
        const float d = tgt - mean;
        ll += -0.5f * (d * d * expf(-lv) + lv + LOG2PI);
      }
    }
    red[threadIdx.x] = ll;
    __syncthreads();
    for (int s = 128; s > 0; s >>= 1) {
      if (threadIdx.x < s) red[threadIdx.x] += red[threadIdx.x + s];
      __syncthreads();
    }
    if (llflag && threadIdx.x == 0) atomicAdd(LL_acc, red[0]);
    __syncthreads();
    if (llflag)
      for (int it = threadIdx.x; it < BATCH * 64; it += 256) Pbuf[it] = 0.f;
    return;
  }
  const int b = blockIdx.x >> 5, ic = blockIdx.x & 31;
  const int wv = threadIdx.x >> 6, lane = threadIdx.x & 63;
  const size_t row0 = (size_t)b * H + ic * 32 + wv * 8;
  u32x4v wq[8];
#pragma unroll
  for (int rr = 0; rr < 8; ++rr)
    wq[rr] = Wq4[(row0 + rr) * 64 + lane];  // row pitch = 1024 B = 64 u32x4
  const float4* fp = (const float4*)(const void*)(f + (size_t)b * H + lane * 16);
  const float4 f0 = fp[0], f1 = fp[1], f2 = fp[2], f3 = fp[3];
  float acc[8];
#pragma unroll
  for (int rr = 0; rr < 8; ++rr) {
    const unsigned int x = wq[rr].x, y = wq[rr].y, z = wq[rr].z, w = wq[rr].w;
    float a = 0.f;
    a = fmaf(i8f(x, 0), f0.x, a); a = fmaf(i8f(x, 1), f0.y, a);
    a = fmaf(i8f(x, 2), f0.z, a); a = fmaf(i8f(x, 3), f0.w, a);
    a = fmaf(i8f(y, 0), f1.x, a); a = fmaf(i8f(y, 1), f1.y, a);
    a = fmaf(i8f(y, 2), f1.z, a); a = fmaf(i8f(y, 3), f1.w, a);
    a = fmaf(i8f(z, 0), f2.x, a); a = fmaf(i8f(z, 1), f2.y, a);
    a = fmaf(i8f(z, 2), f2.z, a); a = fmaf(i8f(z, 3), f2.w, a);
    a = fmaf(i8f(w, 0), f3.x, a); a = fmaf(i8f(w, 1), f3.y, a);
    a = fmaf(i8f(w, 2), f3.z, a); a = fmaf(i8f(w, 3), f3.w, a);
    acc[rr] = a;
  }
#pragma unroll
  for (int rr = 0; rr < 8; ++rr) {
#pragma unroll
    for (int off = 32; off > 0; off >>= 1) acc[rr] += __shfl_xor(acc[rr], off, 64);
  }
  if (lane == 0) {
#pragma unroll
    for (int rr = 0; rr < 8; ++rr) {
      const size_t rid = row0 + rr;
      const float v = tanhf(fmaf(acc[rr], Wsc[rid], bflo((unsigned int)Wlast[rid])));
      h[rid] = v;
      hb[rid] = f2bf(v);
    }
  }
}

// ---------------------------------------------------------------------------
// One-time: Wq[b,i,0:1024] int8 with per-row scale Wsc[b*H+i] = rowmax/127.
// Last column (bias, f[H]=1) stays bf16 in Wlast, excluded from quantization.
// ---------------------------------------------------------------------------
__global__ __launch_bounds__(256) void gen_w(const float* __restrict__ eps,
                                             const float* __restrict__ mu,
                                             const float* __restrict__ sig,
                                             signed char* __restrict__ Wq,
                                             float* __restrict__ Wsc,
                                             unsigned short* __restrict__ Wlast) {
  const size_t rowid = blockIdx.x;  // b*H + i
  const int i = (int)(rowid & (H - 1));
  const int jq = threadIdx.x;
  const float* er = eps + rowid * HP + jq * 4;
  const float* mr = mu + (size_t)i * HP + jq * 4;
  const float* sr = sig + (size_t)i * HP + jq * 4;
  const float w0 = fmaf(sr[0], er[0], mr[0]);
  const float w1 = fmaf(sr[1], er[1], mr[1]);
  const float w2 = fmaf(sr[2], er[2], mr[2]);
  const float w3 = fmaf(sr[3], er[3], mr[3]);
  float m = fmaxf(fmaxf(fabsf(w0), fabsf(w1)), fmaxf(fabsf(w2), fabsf(w3)));
  __shared__ float red[256];
  red[jq] = m;
  __syncthreads();
  for (int s = 128; s > 0; s >>= 1) {
    if (jq < s) red[jq] = fmaxf(red[jq], red[jq + s]);
    __syncthreads();
  }
  const float mx = fmaxf(red[0], 1e-20f);
  const float inv = 127.f / mx;
  int q0 = (int)rintf(w0 * inv);
  int q1 = (int)rintf(w1 * inv);
  int q2 = (int)rintf(w2 * inv);
  int q3 = (int)rintf(w3 * inv);
  q0 = q0 > 127 ? 127 : (q0 < -127 ? -127 : q0);
  q1 = q1 > 127 ? 127 : (q1 < -127 ? -127 : q1);
  q2 = q2 > 127 ? 127 : (q2 < -127 ? -127 : q2);
  q3 = q3 > 127 ? 127 : (q3 < -127 ? -127 : q3);
  const unsigned int pk = ((unsigned int)(unsigned char)(signed char)q0) |
                          (((unsigned int)(unsigned char)(signed char)q1) << 8) |
                          (((unsigned int)(unsigned char)(signed char)q2) << 16) |
                          (((unsigned int)(unsigned char)(signed char)q3) << 24);
  ((unsigned int*)(void*)Wq)[rowid * 256 + jq] = pk;
  if (jq == 0) Wsc[rowid] = mx * (1.f / 127.f);
  if (jq == 255) Wlast[rowid] = f2bf(fmaf(sr[4], er[4], mr[4]));
}

__global__ __launch_bounds__(256) void cvt_bf16(const float* __restrict__ src,
                                                unsigned short* __restrict__ dst, int n) {
  int i = blockIdx.x * 256 + threadIdx.x;
  if (i < n) dst[i] = f2bf(src[i]);
}

// ---------------------------------------------------------------------------
// sigma = exp(0.5*W_logvar) + KL reduction.
// ---------------------------------------------------------------------------
__global__ __launch_bounds__(256) void kl_sigma(const float* __restrict__ Wlv,
                                                const float* __restrict__ pmu,
                                                const float* __restrict__ plv,
                                                const float* __restrict__ Wmu,
                                                float* __restrict__ sigma,
                                                float* __restrict__ KL_acc) {
  const int idx = blockIdx.x * 256 + threadIdx.x;
  float v = 0.f;
  if (idx < H * HP) {
    float qlv = Wlv[idx];
    sigma[idx] = expf(0.5f * qlv);
    float var_q = expf(qlv);
    float p_lv = plv[idx];
    float var_p = expf(p_lv);
    float dmu = Wmu[idx] - pmu[idx];
    v = 0.5f * (p_lv - qlv) + (var_q + dmu * dmu) / (2.f * var_p) - 0.5f;
  }
  __shared__ float red[256];
  red[threadIdx.x] = v;
  __syncthreads();
  for (int s = 128; s > 0; s >>= 1) {
    if (threadIdx.x < s) red[threadIdx.x] += red[threadIdx.x + s];
    __syncthreads();
  }
  if (threadIdx.x == 0) atomicAdd(KL_acc, red[0]);
}

// Final: ll for t'=255 from Pbuf + assemble outputs.
__global__ __launch_bounds__(256) void finalize(const float* __restrict__ acc,
                                                const float* __restrict__ Pbuf,
                                                const float* __restrict__ em_b,
                                                const float* __restrict__ ev_b,
                                                const float* __restrict__ Xt,
                                                float* __restrict__ out) {
  __shared__ float red[256];
  float ll = 0.f;
  for (int it = threadIdx.x; it < BATCH * OUTD; it += 256) {
    const int b = it >> 5, o = it & 31;
    const float mean = Pbuf[b * 64 + o] + em_b[o];
    const float lv = Pbuf[b * 64 + 32 + o] + ev_b[o];
    const float tgt = Xt[b * OUTD + o];
    const float d = tgt - mean;
    ll += -0.5f * (d * d * expf(-lv) + lv + LOG2PI);
  }
  red[threadIdx.x] = ll;
  __syncthreads();
  for (int s = 128; s > 0; s >>= 1) {
    if (threadIdx.x < s) red[threadIdx.x] += red[threadIdx.x + s];
    __syncthreads();
  }
  if (threadIdx.x == 0) {
    const float LLn = (acc[0] + red[0]) / (float)BATCH;
    const float KLn = acc[1] / ((float)TSTEPS * (float)BATCH);
    out[0] = LLn - KLn;
    out[1] = LLn;
    out[2] = KLn;
  }
}

// ---------------------------------------------------------------------------
extern "C" void kernel_launch(void* const* d_in, const int* in_sizes, int n_in,
                              void* d_out, int out_size, void* d_ws, size_t ws_size,
                              hipStream_t stream) {
  const float* X      = (const float*)d_in[0];
  const float* A      = (const float*)d_in[1];
  const float* W_eps  = (const float*)d_in[2];
  const float* W_mu   = (const float*)d_in[3];
  const float* W_lv   = (const float*)d_in[4];
  const float* pW_mu  = (const float*)d_in[5];
  const float* pW_lv  = (const float*)d_in[6];
  const float* enc_w1 = (const float*)d_in[7];
  const float* enc_b1 = (const float*)d_in[8];
  const float* enc_w2 = (const float*)d_in[9];
  const float* enc_b2 = (const float*)d_in[10];
  const float* gw_ih  = (const float*)d_in[11];
  const float* gw_hh  = (const float*)d_in[12];
  const float* gb_ih  = (const float*)d_in[13];
  const float* gb_hh  = (const float*)d_in[14];
  const float* dec_w  = (const float*)d_in[15];
  const float* dec_b  = (const float*)d_in[16];
  const float* em_w   = (const float*)d_in[17];
  const float* em_b   = (const float*)d_in[18];
  const float* ev_w   = (const float*)d_in[19];
  const float* ev_b   = (const float*)d_in[20];
  float* out = (float*)d_out;

  char* base = (char*)d_ws;
  size_t off = 0;
  auto alloc = [&](size_t bytes) -> void* {
    void* p = base + off;
    off += (bytes + 255) & ~(size_t)255;
    return p;
  };
  float* sigma          = (float*)alloc((size_t)H * HP * 4);
  float* hbuf           = (float*)alloc((size_t)BATCH * H * 4);
  unsigned short* hb    = (unsigned short*)alloc((size_t)BATCH * H * 2);
  float* fbuf           = (float*)alloc((size_t)BATCH * H * 4);
  float* Pbuf           = (float*)alloc((size_t)BATCH * 64 * 4);
  float* accb           = (float*)alloc(2 * 4);
  unsigned short* gwhhb = (unsigned short*)alloc((size_t)G3 * H * 2);
  unsigned short* decwb = (unsigned short*)alloc((size_t)H * H * 2);
  unsigned short* headwb= (unsigned short*)alloc((size_t)64 * H * 2);
  unsigned short* Wlast = (unsigned short*)alloc((size_t)BATCH * H * 2);
  float* Wsc            = (float*)alloc((size_t)BATCH * H * 4);
  signed char* Wq       = (signed char*)alloc((size_t)BATCH * H * 1024);

  hipMemsetAsync(accb, 0, 2 * sizeof(float), stream);
  hipMemsetAsync(Pbuf, 0, (size_t)BATCH * 64 * 4, stream);

  kl_sigma<<<(H * HP + 255) / 256, 256, 0, stream>>>(W_lv, pW_mu, pW_lv, W_mu, sigma, accb + 1);
  cvt_bf16<<<(G3 * H) / 256, 256, 0, stream>>>(gw_hh, gwhhb, G3 * H);
  cvt_bf16<<<(H * H) / 256, 256, 0, stream>>>(dec_w, decwb, H * H);
  cvt_bf16<<<(OUTD * H) / 256, 256, 0, stream>>>(em_w, headwb, OUTD * H);
  cvt_bf16<<<(OUTD * H) / 256, 256, 0, stream>>>(ev_w, headwb + OUTD * H, OUTD * H);
  gen_w<<<BATCH * H, 256, 0, stream>>>(W_eps, W_mu, sigma, Wq, Wsc, Wlast);

  // encoder: fbuf = relu(X0 @ enc_w1^T + b1); hbuf = tanh(fbuf @ enc_w2^T + b2)
  gemm_nt<1><<<dim3(H / 32, BATCH / 32), 256, 0, stream>>>(X, enc_w1, enc_b1, fbuf,
                                                           BATCH, H, OUTD);
  gemm_nt<2><<<dim3(H / 32, BATCH / 32), 256, 0, stream>>>(fbuf, enc_w2, enc_b2, hbuf,
                                                           BATCH, H, H);
  cvt_bf16<<<(BATCH * H) / 256, 256, 0, stream>>>(hbuf, hb, BATCH * H);

  for (int t = 1; t <= TSTEPS; ++t) {
    const float* a_t = A + (size_t)(t - 1) * BATCH * ACTD;
    const float* Xprev = X + (size_t)(t - 1) * BATCH * OUTD;  // target for step t-1
    const int grid1 = (t == 1) ? 128 : 160;
    step_fused<<<grid1, 256, 0, stream>>>(hb, hbuf, gwhhb, gw_ih, gb_ih, gb_hh, a_t,
                                          fbuf, decwb, dec_b, headwb, Pbuf, 128);
    wmatvec2<<<4097, 256, 0, stream>>>((const u32x4v*)Wq, Wsc, Wlast, fbuf, hbuf, hb,
                                       Pbuf, em_b, ev_b, Xprev, accb, (t >= 2) ? 1 : 0);
  }
  // dec/heads for the last step (t'=255)
  step_fused<<<32, 256, 0, stream>>>(hb, hbuf, gwhhb, gw_ih, gb_ih, gb_hh, A,
                                     fbuf, decwb, dec_b, headwb, Pbuf, 0);
  finalize<<<1, 256, 0, stream>>>(accb, Pbuf, em_b, ev_b,
                                  X + (size_t)TSTEPS * BATCH * OUTD, out);
}